// Round 3
// baseline (2218.819 us; speedup 1.0000x reference)
//
#include <hip/hip_runtime.h>

typedef unsigned short u16;
typedef __attribute__((ext_vector_type(8))) short s16x8;
typedef __attribute__((ext_vector_type(4))) float f32x4;

__device__ __forceinline__ u16 f2bf(float x) {
    union { float f; unsigned int u; } v; v.f = x;
    return (u16)((v.u + 0x7fffu + ((v.u >> 16) & 1u)) >> 16);
}
__device__ __forceinline__ float bf2f(u16 u) {
    union { unsigned int u; float f; } v; v.u = ((unsigned int)u) << 16;
    return v.f;
}

// ============== Direct-register-load NT GEMM (no LDS, no barriers) ==============
// C[M,N] = A[M,K]*B[N,K]^T. Wave tile 64x64 (MT=NT=4), block = WGM x WGN waves.
// Each wave loads its MFMA fragments straight from global (dwordx4; 64 lanes
// cover 16 rows x 64B = same coalescing as an LDS staging load) with 1-deep
// register prefetch. K-loop has zero __syncthreads -> pure vmcnt dataflow.
// MODE 0: C = acc + bias (+relu); store fp32 (Cf) and/or bf16 (Cb).
// MODE 1: store exp(acc) bf16 (0 for col>=N); per-block row sums -> rspart[bx*M+row].
// Split-K via blockIdx.z (ksplit must be mult of 32); Cf += z*czstride.
template<int WGM, int WGN, int MODE>
__global__ __launch_bounds__(WGM * WGN * 64)
void k_gemmd(const u16* __restrict__ A, int lda, const u16* __restrict__ B, int ldb,
             float* __restrict__ Cf, int ldcf, u16* __restrict__ Cb, int ldcb,
             const float* __restrict__ bias, int relu, float* __restrict__ rspart,
             int M, int N, int Brows, int Ktot, int ksplit, long czstride)
{
    int tid = threadIdx.x, w = tid >> 6, lane = tid & 63;
    int wr = w / WGN, wc = w % WGN, lm = lane & 15, kq = lane >> 4;
    int m0 = blockIdx.y * (WGM * 64), n0 = blockIdx.x * (WGN * 64);
    int kbeg = blockIdx.z * ksplit;
    int kend = kbeg + ksplit; if (kend > Ktot) kend = Ktot;
    if (czstride) Cf += (size_t)blockIdx.z * czstride;

    const u16* ap[4]; const u16* bp[4];
#pragma unroll
    for (int mi = 0; mi < 4; ++mi) {
        int r = m0 + wr * 64 + mi * 16 + lm; if (r > M - 1) r = M - 1;
        ap[mi] = A + (size_t)r * lda + kbeg + kq * 8;
    }
#pragma unroll
    for (int ni = 0; ni < 4; ++ni) {
        int c = n0 + wc * 64 + ni * 16 + lm; if (c > Brows - 1) c = Brows - 1;
        bp[ni] = B + (size_t)c * ldb + kbeg + kq * 8;
    }

    f32x4 acc[4][4] = {};
    int iters = (kend - kbeg) >> 5;

    s16x8 a0[4], b0[4];
#pragma unroll
    for (int i = 0; i < 4; ++i) {
        a0[i] = *(const s16x8*)ap[i]; ap[i] += 32;
        b0[i] = *(const s16x8*)bp[i]; bp[i] += 32;
    }
#pragma unroll 2
    for (int it = 1; it < iters; ++it) {
        s16x8 a1[4], b1[4];
#pragma unroll
        for (int i = 0; i < 4; ++i) {
            a1[i] = *(const s16x8*)ap[i]; ap[i] += 32;
            b1[i] = *(const s16x8*)bp[i]; bp[i] += 32;
        }
#pragma unroll
        for (int mi = 0; mi < 4; ++mi)
#pragma unroll
            for (int ni = 0; ni < 4; ++ni)
                acc[mi][ni] = __builtin_amdgcn_mfma_f32_16x16x32_bf16(a0[mi], b0[ni], acc[mi][ni], 0, 0, 0);
#pragma unroll
        for (int i = 0; i < 4; ++i) { a0[i] = a1[i]; b0[i] = b1[i]; }
    }
#pragma unroll
    for (int mi = 0; mi < 4; ++mi)
#pragma unroll
        for (int ni = 0; ni < 4; ++ni)
            acc[mi][ni] = __builtin_amdgcn_mfma_f32_16x16x32_bf16(a0[mi], b0[ni], acc[mi][ni], 0, 0, 0);

    if constexpr (MODE == 1) {
#pragma unroll
        for (int mi = 0; mi < 4; ++mi) {
            int rb = m0 + wr * 64 + mi * 16 + kq * 4;
#pragma unroll
            for (int r = 0; r < 4; ++r) {
                int row = rb + r;
                float ps = 0.f;
#pragma unroll
                for (int ni = 0; ni < 4; ++ni) {
                    int col = n0 + wc * 64 + ni * 16 + lm;
                    float e = 0.f;
                    if (col < N) { e = __expf(acc[mi][ni][r]); ps += e; }
                    if (row < M) Cb[(size_t)row * ldcb + col] = f2bf(e);
                }
                ps += __shfl_xor(ps, 1); ps += __shfl_xor(ps, 2);
                ps += __shfl_xor(ps, 4); ps += __shfl_xor(ps, 8);
                if (lm == 0 && row < M) rspart[(size_t)blockIdx.x * M + row] = ps;
            }
        }
    } else {
#pragma unroll
        for (int mi = 0; mi < 4; ++mi) {
            int rb = m0 + wr * 64 + mi * 16 + kq * 4;
#pragma unroll
            for (int ni = 0; ni < 4; ++ni) {
                int col = n0 + wc * 64 + ni * 16 + lm;
                if (col >= N) continue;
                float bv = bias ? bias[col] : 0.f;
#pragma unroll
                for (int r = 0; r < 4; ++r) {
                    int row = rb + r;
                    if (row >= M) continue;
                    float v = acc[mi][ni][r] + bv;
                    if (relu) v = fmaxf(v, 0.f);
                    if (Cf) Cf[(size_t)row * ldcf + col] = v;
                    if (Cb) Cb[(size_t)row * ldcb + col] = f2bf(v);
                }
            }
        }
    }
}

// MODE1 partial row-sums -> rowsum[row] (sum over XB x-blocks; coalesced over rows)
__global__ __launch_bounds__(256)
void k_finrs(const float* __restrict__ rspart, int stride, int XB,
             float* __restrict__ rs, int n)
{
    int i = blockIdx.x * 256 + threadIdx.x;
    if (i >= n) return;
    float s = 0.f;
    for (int x = 0; x < XB; ++x) s += rspart[(size_t)x * stride + i];
    rs[i] = s;
}

// ============ transpose+convert fp32[R][C] -> bf16 out[c][r], zero pad ============
__global__ __launch_bounds__(256)
void k_transpose(const float* __restrict__ in, long in_zs, u16* __restrict__ out, long out_zs,
                 int R, int C, int Rpad, int Cpad, int ldout)
{
    __shared__ float tile[32][33];
    const float* src = in + (size_t)blockIdx.z * in_zs;
    u16* dst = out + (size_t)blockIdx.z * out_zs;
    int c0 = blockIdx.x * 32, r0 = blockIdx.y * 32;
    int tx = threadIdx.x, ty = threadIdx.y;
#pragma unroll
    for (int i = 0; i < 32; i += 8) {
        int r = r0 + ty + i, c = c0 + tx;
        tile[ty + i][tx] = (r < R && c < C) ? src[(size_t)r * C + c] : 0.f;
    }
    __syncthreads();
#pragma unroll
    for (int i = 0; i < 32; i += 8) {
        int c = c0 + ty + i, r = r0 + tx;
        if (c < Cpad && r < Rpad) dst[(size_t)c * ldout + r] = f2bf(tile[tx][ty + i]);
    }
}

__global__ __launch_bounds__(256)
void k_cvt(const float* __restrict__ in, u16* __restrict__ out, int n)
{
    for (int i = blockIdx.x * 256 + threadIdx.x; i < n; i += gridDim.x * 256)
        out[i] = f2bf(in[i]);
}

// pack fused biases: sa_qkvB [3][1536], ca_kvB [3][1024]
__global__ __launch_bounds__(256)
void k_biaspack(const float* __restrict__ sbq, const float* __restrict__ sbk, const float* __restrict__ sbv,
                const float* __restrict__ cbk, const float* __restrict__ cbv,
                float* __restrict__ sout, float* __restrict__ cout)
{
    int i = blockIdx.x * 256 + threadIdx.x;
    if (i < 4608) {
        int l = i / 1536, j = i % 1536;
        sout[i] = j < 512 ? sbq[l * 512 + j] : j < 1024 ? sbk[l * 512 + j - 512] : sbv[l * 512 + j - 1024];
    }
    if (i < 3072) {
        int l = i / 1024, j = i % 1024;
        cout[i] = j < 512 ? cbk[l * 512 + j] : cbv[l * 512 + j - 512];
    }
}

// word_emb = text + (1/rowsum) * sum_{z<8} part[z]
__global__ __launch_bounds__(256)
void k_reduce_we(const float* __restrict__ part, long ps,
                 const float* __restrict__ text, const float* __restrict__ rs,
                 float* __restrict__ out, int n)
{
    int i = blockIdx.x * 256 + threadIdx.x;
    if (i >= n) return;
    float s = 0.f;
#pragma unroll
    for (int z = 0; z < 8; ++z) s += part[(size_t)z * ps + i];
    out[i] = text[i] + s * (1.f / rs[i >> 9]);
}

// ---------------- LayerNorm over D=512; optional residual; optional bf16 mirror ----------------
__global__ __launch_bounds__(256)
void k_ln(const float* __restrict__ xin, const float* __restrict__ res,
          const float* __restrict__ g, const float* __restrict__ b,
          float* __restrict__ out, u16* __restrict__ out_bf, int ldbf)
{
    int row = blockIdx.x, t = threadIdx.x;
    size_t base = (size_t)row * 512;
    float v0 = xin[base + t], v1 = xin[base + t + 256];
    if (res) { v0 += res[base + t]; v1 += res[base + t + 256]; }
    float s1 = v0 + v1, s2 = v0 * v0 + v1 * v1;
#pragma unroll
    for (int o = 32; o > 0; o >>= 1) { s1 += __shfl_down(s1, o); s2 += __shfl_down(s2, o); }
    __shared__ float a1[4], a2[4], mr[2];
    if ((t & 63) == 0) { a1[t >> 6] = s1; a2[t >> 6] = s2; }
    __syncthreads();
    if (t == 0) {
        float S1 = a1[0] + a1[1] + a1[2] + a1[3];
        float S2 = a2[0] + a2[1] + a2[2] + a2[3];
        float m = S1 * (1.f / 512.f);
        float var = S2 * (1.f / 512.f) - m * m;
        mr[0] = m; mr[1] = rsqrtf(var + 1e-5f);
    }
    __syncthreads();
    float m = mr[0], rs = mr[1];
    float y0 = (v0 - m) * rs * g[t] + b[t];
    float y1 = (v1 - m) * rs * g[t + 256] + b[t + 256];
    out[base + t] = y0; out[base + t + 256] = y1;
    if (out_bf) {
        size_t bb = (size_t)row * ldbf;
        out_bf[bb + t] = f2bf(y0); out_bf[bb + t + 256] = f2bf(y1);
    }
}

// ---------------- x[b,s,:] = sum_n w[s,n] * we[b,n,:]; fp32 + bf16 (ld 1024) ----------------
__global__ __launch_bounds__(256)
void k_wmap(const float* __restrict__ w, const float* __restrict__ we,
            float* __restrict__ x, u16* __restrict__ x_bf)
{
    int bid = blockIdx.x;
    int b = bid / 17, s = bid % 17;
    int t = threadIdx.x;
    const float* wr = w + s * 144;
    const float* base = we + (size_t)b * 144 * 512;
    float a0 = 0.f, a1 = 0.f;
    for (int n = 0; n < 144; ++n) {
        float wv = wr[n];
        a0 += wv * base[(size_t)n * 512 + t];
        a1 += wv * base[(size_t)n * 512 + t + 256];
    }
    size_t r = (size_t)(b * 17 + s);
    x[r * 512 + t] = a0; x[r * 512 + t + 256] = a1;
    x_bf[r * 1024 + t] = f2bf(a0); x_bf[r * 1024 + t + 256] = f2bf(a1);
}

// ---------------- self-attention: fused QKV bf16 in (ld 1536), bf16 out ----------------
__global__ __launch_bounds__(128)
void k_attn_self(const u16* __restrict__ qkv, u16* __restrict__ o)
{
    int b = blockIdx.x >> 3, h = blockIdx.x & 7;
    __shared__ float qs[17][65], ks[17][65], vs[17][65], ps[17][18];
    int t = threadIdx.x;
    for (int i = t; i < 17 * 64; i += 128) {
        int s = i >> 6, d = i & 63;
        size_t g = ((size_t)(b * 17 + s)) * 1536 + h * 64 + d;
        qs[s][d] = bf2f(qkv[g]); ks[s][d] = bf2f(qkv[g + 512]); vs[s][d] = bf2f(qkv[g + 1024]);
    }
    __syncthreads();
    for (int i = t; i < 17 * 17; i += 128) {
        int r = i / 17, c = i % 17;
        float a = 0.f;
#pragma unroll
        for (int d = 0; d < 64; ++d) a += qs[r][d] * ks[c][d];
        ps[r][c] = a * 0.125f;
    }
    __syncthreads();
    if (t < 17) {
        float mxv = -1e30f;
        for (int c = 0; c < 17; ++c) mxv = fmaxf(mxv, ps[t][c]);
        float sm = 0.f;
        for (int c = 0; c < 17; ++c) { float e = __expf(ps[t][c] - mxv); ps[t][c] = e; sm += e; }
        float inv = 1.f / sm;
        for (int c = 0; c < 17; ++c) ps[t][c] *= inv;
    }
    __syncthreads();
    for (int i = t; i < 17 * 64; i += 128) {
        int s = i >> 6, d = i & 63;
        float a = 0.f;
#pragma unroll
        for (int j = 0; j < 17; ++j) a += ps[s][j] * vs[j][d];
        o[((size_t)(b * 17 + s)) * 512 + h * 64 + d] = f2bf(a);
    }
}

// ---------------- cross-attention: q bf16 (ld 512), kv = enc_kv slice (ld 3072) ----------------
__global__ __launch_bounds__(256)
void k_attn_cross(const u16* __restrict__ q, const u16* __restrict__ kv, u16* __restrict__ o)
{
    int b = blockIdx.x >> 3, h = blockIdx.x & 7;
    __shared__ float qs[17][65];
    __shared__ float ps[17][145];
    int t = threadIdx.x;
    for (int i = t; i < 17 * 64; i += 256) {
        int s = i >> 6, d = i & 63;
        qs[s][d] = bf2f(q[((size_t)(b * 17 + s)) * 512 + h * 64 + d]);
    }
    __syncthreads();
    for (int i = t; i < 17 * 144; i += 256) {
        int r = i / 144, c = i % 144;
        const u16* kr = kv + ((size_t)(b * 144 + c)) * 3072 + h * 64;
        float a = 0.f;
#pragma unroll
        for (int d = 0; d < 64; ++d) a += qs[r][d] * bf2f(kr[d]);
        ps[r][c] = a * 0.125f;
    }
    __syncthreads();
    if (t < 17) {
        float mxv = -1e30f;
        for (int c = 0; c < 144; ++c) mxv = fmaxf(mxv, ps[t][c]);
        float sm = 0.f;
        for (int c = 0; c < 144; ++c) { float e = __expf(ps[t][c] - mxv); ps[t][c] = e; sm += e; }
        float inv = 1.f / sm;
        for (int c = 0; c < 144; ++c) ps[t][c] *= inv;
    }
    __syncthreads();
    for (int i = t; i < 17 * 64; i += 256) {
        int s = i >> 6, d = i & 63;
        float a = 0.f;
        for (int j = 0; j < 144; ++j)
            a += ps[s][j] * bf2f(kv[((size_t)(b * 144 + j)) * 3072 + 512 + h * 64 + d]);
        o[((size_t)(b * 17 + s)) * 512 + h * 64 + d] = f2bf(a);
    }
}

__global__ __launch_bounds__(256)
void k_blend(const float* __restrict__ x, const float* __restrict__ xs,
             const float* __restrict__ gl, float* __restrict__ y, int n)
{
    int i = blockIdx.x * 256 + threadIdx.x;
    if (i < n) {
        float s = 1.f / (1.f + __expf(-gl[i]));
        y[i] = x[i] * s + xs[i] * (1.f - s);
    }
}

extern "C" void kernel_launch(void* const* d_in, const int* in_sizes, int n_in,
                              void* d_out, int out_size, void* d_ws, size_t ws_size,
                              hipStream_t stream)
{
    (void)in_sizes; (void)out_size;
    if (n_in < 39) return;
    const float* enc    = (const float*)d_in[0];
    const float* wmat   = (const float*)d_in[1];
    const float* i2t_w  = (const float*)d_in[2];
    const float* i2t_b  = (const float*)d_in[3];
    const float* i2t_g  = (const float*)d_in[4];
    const float* i2t_bb = (const float*)d_in[5];
    const float* emb    = (const float*)d_in[6];
    const float* gen_w  = (const float*)d_in[7];
    const float* gen_b  = (const float*)d_in[8];
    const float* a_w    = (const float*)d_in[9];
    const float* a_b    = (const float*)d_in[10];
    const float* fln_g  = (const float*)d_in[11];
    const float* fln_b  = (const float*)d_in[12];
    const float* sa_wq  = (const float*)d_in[13];
    const float* sa_bq  = (const float*)d_in[14];
    const float* sa_wk  = (const float*)d_in[15];
    const float* sa_bk  = (const float*)d_in[16];
    const float* sa_wv  = (const float*)d_in[17];
    const float* sa_bv  = (const float*)d_in[18];
    const float* sa_wo  = (const float*)d_in[19];
    const float* sa_bo  = (const float*)d_in[20];
    const float* ca_wq  = (const float*)d_in[21];
    const float* ca_bq  = (const float*)d_in[22];
    const float* ca_wk  = (const float*)d_in[23];
    const float* ca_bk  = (const float*)d_in[24];
    const float* ca_wv  = (const float*)d_in[25];
    const float* ca_bv  = (const float*)d_in[26];
    const float* ca_wo  = (const float*)d_in[27];
    const float* ca_bo  = (const float*)d_in[28];
    const float* ln1_g  = (const float*)d_in[29];
    const float* ln1_b  = (const float*)d_in[30];
    const float* ln2_g  = (const float*)d_in[31];
    const float* ln2_b  = (const float*)d_in[32];
    const float* ln3_g  = (const float*)d_in[33];
    const float* ln3_b  = (const float*)d_in[34];
    const float* fc1_w  = (const float*)d_in[35];
    const float* fc1_b  = (const float*)d_in[36];
    const float* fc2_w  = (const float*)d_in[37];
    const float* fc2_b  = (const float*)d_in[38];

    char* ws = (char*)d_ws;
    size_t off = 0;
    auto AL = [](size_t x) { return (x + 255) & ~(size_t)255; };
    auto alloc = [&](size_t bytes) { char* p = ws + off; off += AL(bytes); return p; };

    // ---- persistent bf16 transposed weights ----
    u16* i2t_wT  = (u16*)alloc((size_t)512 * 512 * 2);
    u16* sa_qkvT = (u16*)alloc((size_t)3 * 1536 * 512 * 2);
    u16* sa_woT  = (u16*)alloc((size_t)3 * 512 * 512 * 2);
    u16* ca_qT   = (u16*)alloc((size_t)3 * 512 * 512 * 2);
    u16* ca_kvT  = (u16*)alloc((size_t)3 * 1024 * 512 * 2);
    u16* ca_woT  = (u16*)alloc((size_t)3 * 512 * 512 * 2);
    u16* fc1T    = (u16*)alloc((size_t)3 * 2048 * 512 * 2);
    u16* fc2T    = (u16*)alloc((size_t)3 * 512 * 2048 * 2);
    u16* a_wT    = (u16*)alloc((size_t)512 * 1024 * 2);
    u16* gen_wT  = (u16*)alloc((size_t)10112 * 512 * 2);
    u16* embB    = (u16*)alloc((size_t)10112 * 512 * 2);
    u16* embT    = (u16*)alloc((size_t)512 * 10112 * 2);
    u16* enc_bf  = (u16*)alloc((size_t)9216 * 512 * 2);
    float* text_f   = (float*)alloc((size_t)9216 * 512 * 4);
    u16*   text_bf  = (u16*)alloc((size_t)9216 * 512 * 2);
    float* word_emb = (float*)alloc((size_t)9216 * 512 * 4);
    float* rowsum   = (float*)alloc(9216 * 4);
    float* rspart   = (float*)alloc((size_t)79 * 9216 * 4);
    float* sa_qkvB  = (float*)alloc(4608 * 4);
    float* ca_kvB   = (float*)alloc(3072 * 4);

    // ---- decoder-phase buffers ----
    u16* enc_kv = (u16*)alloc((size_t)9216 * 3072 * 2);
    u16* xcat   = (u16*)alloc((size_t)1088 * 1024 * 2);   // cols 0-511: x, 512-1023: x_self
    u16* tqkv   = (u16*)alloc((size_t)1088 * 1536 * 2);
    u16* attnb  = (u16*)alloc((size_t)1088 * 512 * 2);
    u16* q_bf   = (u16*)alloc((size_t)1088 * 512 * 2);
    u16* ffn    = (u16*)alloc((size_t)1088 * 2048 * 2);
    float* x_f   = (float*)alloc((size_t)1088 * 512 * 4);
    float* xs_f  = (float*)alloc((size_t)1088 * 512 * 4);
    float* tmp_f = (float*)alloc((size_t)1088 * 512 * 4);
    float* glin  = (float*)alloc((size_t)1088 * 512 * 4);

    // ---- stage-B chunked region: logits [chunk][10112] bf16 + part [8][chunk][512] f32 ----
    size_t lo = off;
    long budget = (ws_size > lo) ? (long)(ws_size - lo) : 0;
    long perrow = 10112L * 2 + 8L * 512 * 4;
    int chunk = (int)((budget / perrow) & ~(long)127);
    if (chunk > 9216) chunk = 9216;
    if (chunk < 128) chunk = 128;
    u16* logits = (u16*)(ws + lo);
    float* part = (float*)(ws + lo + AL((size_t)chunk * 10112 * 2));
    long pstride = (long)chunk * 512;

    // ---- weight transposes / converts ----
    dim3 tb(32, 8);
    auto T = [&](const float* in, long izs, u16* out, long ozs, int R, int C, int Rp, int Cp, int ldo, int nz) {
        k_transpose<<<dim3((Cp + 31) / 32, (Rp + 31) / 32, nz), tb, 0, stream>>>(in, izs, out, ozs, R, C, Rp, Cp, ldo);
    };
    T(i2t_w, 0, i2t_wT, 0, 512, 512, 512, 512, 512, 1);
    T(sa_wq, 512 * 512, sa_qkvT,             1536 * 512, 512, 512, 512, 512, 512, 3);
    T(sa_wk, 512 * 512, sa_qkvT + 512 * 512, 1536 * 512, 512, 512, 512, 512, 512, 3);
    T(sa_wv, 512 * 512, sa_qkvT + 1024 * 512,1536 * 512, 512, 512, 512, 512, 512, 3);
    T(sa_wo, 512 * 512, sa_woT, 512 * 512, 512, 512, 512, 512, 512, 3);
    T(ca_wq, 512 * 512, ca_qT,  512 * 512, 512, 512, 512, 512, 512, 3);
    T(ca_wk, 512 * 512, ca_kvT,             1024 * 512, 512, 512, 512, 512, 512, 3);
    T(ca_wv, 512 * 512, ca_kvT + 512 * 512, 1024 * 512, 512, 512, 512, 512, 512, 3);
    T(ca_wo, 512 * 512, ca_woT, 512 * 512, 512, 512, 512, 512, 512, 3);
    T(fc1_w, (long)512 * 2048, fc1T, (long)2048 * 512, 512, 2048, 512, 2048, 512, 3);
    T(fc2_w, (long)2048 * 512, fc2T, (long)512 * 2048, 2048, 512, 2048, 512, 2048, 3);
    T(a_w, 0, a_wT, 0, 1024, 512, 1024, 512, 1024, 1);
    T(gen_w, 0, gen_wT, 0, 512, 10000, 512, 10112, 512, 1);
    T(emb, 0, embT, 0, 10000, 512, 10112, 512, 10112, 1);
    k_cvt<<<2048, 256, 0, stream>>>(emb, embB, 10000 * 512);
    k_cvt<<<2048, 256, 0, stream>>>(enc, enc_bf, 9216 * 512);
    k_biaspack<<<18, 256, 0, stream>>>(sa_bq, sa_bk, sa_bv, ca_bk, ca_bv, sa_qkvB, ca_kvB);

    // ---- stage A: text = LN(enc @ i2t_w + b) ----
    k_gemmd<2, 2, 0><<<dim3(4, 72), 256, 0, stream>>>(
        enc_bf, 512, i2t_wT, 512, word_emb, 512, nullptr, 0, i2t_b, 0, nullptr,
        9216, 512, 512, 512, 512, 0);
    k_ln<<<9216, 256, 0, stream>>>(word_emb, nullptr, i2t_g, i2t_bb, text_f, text_bf, 512);

    // ---- stage B: word_emb = text + softmax(text @ emb^T) @ emb (fused exp, no atomics) ----
    for (int r0 = 0; r0 < 9216; r0 += chunk) {
        int CR = (9216 - r0 < chunk) ? (9216 - r0) : chunk;
        k_gemmd<2, 2, 1><<<dim3(79, CR / 128), 256, 0, stream>>>(
            text_bf + (size_t)r0 * 512, 512, embB, 512, nullptr, 0, logits, 10112,
            nullptr, 0, rspart, CR, 10000, 10112, 512, 512, 0);
        k_finrs<<<(CR + 255) / 256, 256, 0, stream>>>(rspart, CR, 79, rowsum + r0, CR);
        k_gemmd<2, 2, 0><<<dim3(4, CR / 128, 8), 256, 0, stream>>>(
            logits, 10112, embT, 10112, part, 512, nullptr, 0, nullptr, 0, nullptr,
            CR, 512, 512, 10112, 1280, pstride);
        k_reduce_we<<<(CR * 512 + 255) / 256, 256, 0, stream>>>(
            part, pstride, text_f + (size_t)r0 * 512, rowsum + r0,
            word_emb + (size_t)r0 * 512, CR * 512);
    }

    // ---- stage C ----
    k_wmap<<<1088, 256, 0, stream>>>(wmat, word_emb, x_f, xcat);

    // ---- cross K/V for all 3 layers in one GEMM ----
    k_gemmd<2, 2, 0><<<dim3(24, 72), 256, 0, stream>>>(
        enc_bf, 512, ca_kvT, 512, nullptr, 0, enc_kv, 3072, ca_kvB, 0, nullptr,
        9216, 3072, 3072, 512, 512, 0);

    // ---- stage D: decoder layers (M=1088 = 17 x 64 exactly) ----
    for (int l = 0; l < 3; ++l) {
        size_t wo = (size_t)l * 512 * 512;
        // fused QKV
        k_gemmd<1, 2, 0><<<dim3(12, 17), 128, 0, stream>>>(
            xcat, 1024, sa_qkvT + (size_t)l * 1536 * 512, 512, nullptr, 0, tqkv, 1536,
            sa_qkvB + l * 1536, 0, nullptr, 1088, 1536, 1536, 512, 512, 0);
        k_attn_self<<<512, 128, 0, stream>>>(tqkv, attnb);
        k_gemmd<1, 2, 0><<<dim3(4, 17), 128, 0, stream>>>(
            attnb, 512, sa_woT + wo, 512, xs_f, 512, xcat + 512, 1024,
            sa_bo + l * 512, 0, nullptr, 1088, 512, 512, 512, 512, 0);
        k_ln<<<1088, 256, 0, stream>>>(xs_f, x_f, ln1_g + l * 512, ln1_b + l * 512, x_f, xcat, 1024);
        // cross attention
        k_gemmd<1, 2, 0><<<dim3(4, 17), 128, 0, stream>>>(
            xcat, 1024, ca_qT + wo, 512, nullptr, 0, q_bf, 512,
            ca_bq + l * 512, 0, nullptr, 1088, 512, 512, 512, 512, 0);
        k_attn_cross<<<512, 256, 0, stream>>>(q_bf, enc_kv + l * 1024, attnb);
        k_gemmd<1, 2, 0><<<dim3(4, 17), 128, 0, stream>>>(
            attnb, 512, ca_woT + wo, 512, tmp_f, 512, nullptr, 0,
            ca_bo + l * 512, 0, nullptr, 1088, 512, 512, 512, 512, 0);
        k_ln<<<1088, 256, 0, stream>>>(tmp_f, x_f, ln2_g + l * 512, ln2_b + l * 512, x_f, xcat, 1024);
        // FFN
        k_gemmd<1, 2, 0><<<dim3(16, 17), 128, 0, stream>>>(
            xcat, 1024, fc1T + (size_t)l * 2048 * 512, 512, nullptr, 0, ffn, 2048,
            fc1_b + l * 2048, 1, nullptr, 1088, 2048, 2048, 512, 512, 0);
        k_gemmd<1, 2, 0><<<dim3(4, 17), 128, 0, stream>>>(
            ffn, 2048, fc2T + (size_t)l * 512 * 2048, 2048, tmp_f, 512, nullptr, 0,
            fc2_b + l * 512, 0, nullptr, 1088, 512, 512, 2048, 2048, 0);
        k_ln<<<1088, 256, 0, stream>>>(tmp_f, x_f, ln3_g + l * 512, ln3_b + l * 512, x_f, xcat, 1024);
    }

    // ---- stage E: gated blend (single K=1024 GEMM over [x | x_self]) ----
    k_gemmd<1, 2, 0><<<dim3(4, 17), 128, 0, stream>>>(
        xcat, 1024, a_wT, 1024, glin, 512, nullptr, 0, a_b, 0, nullptr,
        1088, 512, 512, 1024, 1024, 0);
    k_blend<<<2176, 256, 0, stream>>>(x_f, xs_f, glin, tmp_f, 1088 * 512);
    k_ln<<<1088, 256, 0, stream>>>(tmp_f, nullptr, fln_g, fln_b, x_f, xcat, 1024);

    // ---- stage F: generator ----
    k_gemmd<1, 2, 0><<<dim3(79, 17), 128, 0, stream>>>(
        xcat, 1024, gen_wT, 512, (float*)d_out, 10000, nullptr, 0, gen_b, 0, nullptr,
        1088, 10000, 10112, 512, 512, 0);
}

// Round 4
// 1438.977 us; speedup vs baseline: 1.5419x; 1.5419x over previous
//
#include <hip/hip_runtime.h>

typedef unsigned short u16;
typedef __attribute__((ext_vector_type(8))) short s16x8;
typedef __attribute__((ext_vector_type(4))) float f32x4;

__device__ __forceinline__ u16 f2bf(float x) {
    union { float f; unsigned int u; } v; v.f = x;
    return (u16)((v.u + 0x7fffu + ((v.u >> 16) & 1u)) >> 16);
}
__device__ __forceinline__ float bf2f(u16 u) {
    union { unsigned int u; float f; } v; v.u = ((unsigned int)u) << 16;
    return v.f;
}

__device__ __forceinline__ void gload_lds16(const void* g, void* l) {
    __builtin_amdgcn_global_load_lds((const __attribute__((address_space(1))) void*)g,
                                     (__attribute__((address_space(3))) void*)l, 16, 0, 0);
}

// ================= NT GEMM, staged LDS, BK=64, XOR-swizzled slots =================
// C[M,N] = A[M,K]*B[N,K]^T, all bf16 operands, fp32 acc.
// LDS tile row = 64 shorts (8 chunks of 8). Chunk c of row r stored at slot
// c^(r&7); the swizzle is applied to the GLOBAL source index at staging time so
// the global_load_lds LDS destination stays linear (wave-uniform base+lane*16).
// Fragment ds_read_b128 at slot (c^(m&7)) -> 8 bank groups, 2-way max (free).
// K-ranges must be multiples of 64. M must be a multiple of BM; B rows padded
// to a multiple of BN (epilogue masks col < N).
// MODE 0: C = acc + bias (+relu); store fp32 (Cf,ldcf) and/or bf16 (Cb,ldcb).
// MODE 1: store exp(acc) bf16 (0 for col>=N); block row-sums -> rspart[bx*M+row].
// Split-K via blockIdx.z; Cf += z*czstride.
template<int BM, int BN, int WM, int WN, int MODE>
__global__ __launch_bounds__(256)
void k_gemm(const u16* __restrict__ A, int lda, const u16* __restrict__ B, int ldb,
            float* __restrict__ Cf, int ldcf, u16* __restrict__ Cb, int ldcb,
            const float* __restrict__ bias, int relu, float* __restrict__ rspart,
            int M, int N, int Ktot, int ksplit, long czstride)
{
    constexpr int MT = WM / 16, NT = WN / 16, WC = BN / WN;
    constexpr int AI = BM / 32, BI = BN / 32;   // staging rounds (256 chunks = 32 rows each)
    __shared__ __align__(16) u16 As[BM * 64];
    __shared__ __align__(16) u16 Bs[BN * 64];
    int tid = threadIdx.x, w = tid >> 6, lane = tid & 63;
    int m0 = blockIdx.y * BM, n0 = blockIdx.x * BN;
    int wr = w / WC, wc = w % WC, lm = lane & 15, kq = lane >> 4;
    int kbeg = blockIdx.z * ksplit;
    int kend = kbeg + ksplit; if (kend > Ktot) kend = Ktot;
    if (czstride) Cf += (size_t)blockIdx.z * czstride;

    f32x4 acc[MT][NT] = {};

    for (int k0 = kbeg; k0 < kend; k0 += 64) {
        __syncthreads();
#pragma unroll
        for (int i = 0; i < AI; ++i) {
            int cid = i * 256 + tid;
            int r = cid >> 3, gc = (cid & 7) ^ (r & 7);
            gload_lds16(A + (size_t)(m0 + r) * lda + k0 + gc * 8,
                        As + (size_t)(i * 256 + w * 64) * 8);
        }
#pragma unroll
        for (int i = 0; i < BI; ++i) {
            int cid = i * 256 + tid;
            int r = cid >> 3, gc = (cid & 7) ^ (r & 7);
            gload_lds16(B + (size_t)(n0 + r) * ldb + k0 + gc * 8,
                        Bs + (size_t)(i * 256 + w * 64) * 8);
        }
        __syncthreads();   // drains vmcnt -> tiles complete
#pragma unroll
        for (int kk = 0; kk < 2; ++kk) {
            int c = kk * 4 + kq;
            s16x8 af[MT], bfr[NT];
#pragma unroll
            for (int mi = 0; mi < MT; ++mi) {
                int m = wr * WM + mi * 16 + lm;
                af[mi] = *(const s16x8*)&As[(m << 6) + ((c ^ (m & 7)) << 3)];
            }
#pragma unroll
            for (int ni = 0; ni < NT; ++ni) {
                int n = wc * WN + ni * 16 + lm;
                bfr[ni] = *(const s16x8*)&Bs[(n << 6) + ((c ^ (n & 7)) << 3)];
            }
#pragma unroll
            for (int mi = 0; mi < MT; ++mi)
#pragma unroll
                for (int ni = 0; ni < NT; ++ni)
                    acc[mi][ni] = __builtin_amdgcn_mfma_f32_16x16x32_bf16(af[mi], bfr[ni], acc[mi][ni], 0, 0, 0);
        }
    }

    if constexpr (MODE == 1) {
#pragma unroll
        for (int mi = 0; mi < MT; ++mi) {
            int rb = m0 + wr * WM + mi * 16 + kq * 4;
#pragma unroll
            for (int r = 0; r < 4; ++r) {
                int row = rb + r;
                float ps = 0.f;
#pragma unroll
                for (int ni = 0; ni < NT; ++ni) {
                    int col = n0 + wc * WN + ni * 16 + lm;
                    float e = 0.f;
                    if (col < N) { e = __expf(acc[mi][ni][r]); ps += e; }
                    if (row < M) Cb[(size_t)row * ldcb + col] = f2bf(e);
                }
                ps += __shfl_xor(ps, 1); ps += __shfl_xor(ps, 2);
                ps += __shfl_xor(ps, 4); ps += __shfl_xor(ps, 8);
                if (lm == 0 && row < M) rspart[(size_t)blockIdx.x * M + row] = ps;
            }
        }
    } else {
#pragma unroll
        for (int mi = 0; mi < MT; ++mi) {
            int rb = m0 + wr * WM + mi * 16 + kq * 4;
#pragma unroll
            for (int ni = 0; ni < NT; ++ni) {
                int col = n0 + wc * WN + ni * 16 + lm;
                if (col >= N) continue;
                float bv = bias ? bias[col] : 0.f;
#pragma unroll
                for (int r = 0; r < 4; ++r) {
                    int row = rb + r;
                    if (row >= M) continue;
                    float v = acc[mi][ni][r] + bv;
                    if (relu) v = fmaxf(v, 0.f);
                    if (Cf) Cf[(size_t)row * ldcf + col] = v;
                    if (Cb) Cb[(size_t)row * ldcb + col] = f2bf(v);
                }
            }
        }
    }
}

// MODE1 partial row-sums -> rowsum[row]
__global__ __launch_bounds__(256)
void k_finrs(const float* __restrict__ rspart, int stride, int XB,
             float* __restrict__ rs, int n)
{
    int i = blockIdx.x * 256 + threadIdx.x;
    if (i >= n) return;
    float s = 0.f;
    for (int x = 0; x < XB; ++x) s += rspart[(size_t)x * stride + i];
    rs[i] = s;
}

// ============ mega-transpose: all weight fp32[R][C] -> bf16 dst[c][r] in ONE launch ============
struct TD { const float* src; u16* dst; long izs, ozs; int R, C, Rp, Cp, ldo, tx, ty, nb; };
struct TPack { TD d[14]; int nd; };

__global__ __launch_bounds__(256)
void k_mt(TPack p)
{
    __shared__ float tile[32][33];
    int id = blockIdx.x, di = 0;
    while (di < p.nd - 1 && id >= p.d[di].nb) { id -= p.d[di].nb; ++di; }
    TD d = p.d[di];
    int per = d.tx * d.ty;
    int z = id / per, rem = id - z * per;
    int by = rem / d.tx, bx = rem - by * d.tx;
    const float* src = d.src + (size_t)z * d.izs;
    u16* dst = d.dst + (size_t)z * d.ozs;
    int c0 = bx * 32, r0 = by * 32;
    int tx = threadIdx.x & 31, ty = threadIdx.x >> 5;
#pragma unroll
    for (int i = 0; i < 32; i += 8) {
        int r = r0 + ty + i, c = c0 + tx;
        tile[ty + i][tx] = (r < d.R && c < d.C) ? src[(size_t)r * d.C + c] : 0.f;
    }
    __syncthreads();
#pragma unroll
    for (int i = 0; i < 32; i += 8) {
        int c = c0 + ty + i, r = r0 + tx;
        if (c < d.Cp && r < d.Rp) dst[(size_t)c * d.ldo + r] = f2bf(tile[tx][ty + i]);
    }
}

// two flat fp32->bf16 converts in one launch
__global__ __launch_bounds__(256)
void k_cvt2(const float* __restrict__ in1, u16* __restrict__ out1, int n1,
            const float* __restrict__ in2, u16* __restrict__ out2, int n2)
{
    for (int i = blockIdx.x * 256 + threadIdx.x; i < n1 + n2; i += gridDim.x * 256) {
        if (i < n1) out1[i] = f2bf(in1[i]);
        else        out2[i - n1] = f2bf(in2[i - n1]);
    }
}

// pack fused biases: sa_qkvB [3][1536], ca_kvB [3][1024]
__global__ __launch_bounds__(256)
void k_biaspack(const float* __restrict__ sbq, const float* __restrict__ sbk, const float* __restrict__ sbv,
                const float* __restrict__ cbk, const float* __restrict__ cbv,
                float* __restrict__ sout, float* __restrict__ cout)
{
    int i = blockIdx.x * 256 + threadIdx.x;
    if (i < 4608) {
        int l = i / 1536, j = i % 1536;
        sout[i] = j < 512 ? sbq[l * 512 + j] : j < 1024 ? sbk[l * 512 + j - 512] : sbv[l * 512 + j - 1024];
    }
    if (i < 3072) {
        int l = i / 1024, j = i % 1024;
        cout[i] = j < 512 ? cbk[l * 512 + j] : cbv[l * 512 + j - 512];
    }
}

// word_emb = text + (1/rowsum) * sum_{z<8} part[z]
__global__ __launch_bounds__(256)
void k_reduce_we(const float* __restrict__ part, long ps,
                 const float* __restrict__ text, const float* __restrict__ rs,
                 float* __restrict__ out, int n)
{
    int i = blockIdx.x * 256 + threadIdx.x;
    if (i >= n) return;
    float s = 0.f;
#pragma unroll
    for (int z = 0; z < 8; ++z) s += part[(size_t)z * ps + i];
    out[i] = text[i] + s * (1.f / rs[i >> 9]);
}

// ---------------- LayerNorm over D=512; optional residual OR sigmoid-gate blend ----------------
__global__ __launch_bounds__(256)
void k_ln(const float* __restrict__ xin, const float* __restrict__ res,
          const float* __restrict__ g, const float* __restrict__ b,
          float* __restrict__ out, u16* __restrict__ out_bf, int ldbf,
          const float* __restrict__ gl, const float* __restrict__ xs)
{
    int row = blockIdx.x, t = threadIdx.x;
    size_t base = (size_t)row * 512;
    float v0 = xin[base + t], v1 = xin[base + t + 256];
    if (res) { v0 += res[base + t]; v1 += res[base + t + 256]; }
    if (gl) {
        float s0 = 1.f / (1.f + __expf(-gl[base + t]));
        float s1 = 1.f / (1.f + __expf(-gl[base + t + 256]));
        v0 = v0 * s0 + xs[base + t] * (1.f - s0);
        v1 = v1 * s1 + xs[base + t + 256] * (1.f - s1);
    }
    float s1s = v0 + v1, s2s = v0 * v0 + v1 * v1;
#pragma unroll
    for (int o = 32; o > 0; o >>= 1) { s1s += __shfl_down(s1s, o); s2s += __shfl_down(s2s, o); }
    __shared__ float a1[4], a2[4], mr[2];
    if ((t & 63) == 0) { a1[t >> 6] = s1s; a2[t >> 6] = s2s; }
    __syncthreads();
    if (t == 0) {
        float S1 = a1[0] + a1[1] + a1[2] + a1[3];
        float S2 = a2[0] + a2[1] + a2[2] + a2[3];
        float m = S1 * (1.f / 512.f);
        float var = S2 * (1.f / 512.f) - m * m;
        mr[0] = m; mr[1] = rsqrtf(var + 1e-5f);
    }
    __syncthreads();
    float m = mr[0], rs = mr[1];
    float y0 = (v0 - m) * rs * g[t] + b[t];
    float y1 = (v1 - m) * rs * g[t + 256] + b[t + 256];
    out[base + t] = y0; out[base + t + 256] = y1;
    if (out_bf) {
        size_t bb = (size_t)row * ldbf;
        out_bf[bb + t] = f2bf(y0); out_bf[bb + t + 256] = f2bf(y1);
    }
}

// ---------------- x[b,s,:] = sum_n w[s,n] * we[b,n,:]; fp32 + bf16 (ld 1024) ----------------
__global__ __launch_bounds__(256)
void k_wmap(const float* __restrict__ w, const float* __restrict__ we,
            float* __restrict__ x, u16* __restrict__ x_bf)
{
    int bid = blockIdx.x;
    int b = bid / 17, s = bid % 17;
    int t = threadIdx.x;
    const float* wr = w + s * 144;
    const float* base = we + (size_t)b * 144 * 512;
    float a0 = 0.f, a1 = 0.f;
    for (int n = 0; n < 144; ++n) {
        float wv = wr[n];
        a0 += wv * base[(size_t)n * 512 + t];
        a1 += wv * base[(size_t)n * 512 + t + 256];
    }
    size_t r = (size_t)(b * 17 + s);
    x[r * 512 + t] = a0; x[r * 512 + t + 256] = a1;
    x_bf[r * 1024 + t] = f2bf(a0); x_bf[r * 1024 + t + 256] = f2bf(a1);
}

// ---------------- self-attention: fused QKV bf16 in (ld 1536), bf16 out ----------------
__global__ __launch_bounds__(128)
void k_attn_self(const u16* __restrict__ qkv, u16* __restrict__ o)
{
    int b = blockIdx.x >> 3, h = blockIdx.x & 7;
    __shared__ float qs[17][65], ks[17][65], vs[17][65], ps[17][18];
    int t = threadIdx.x;
    for (int i = t; i < 17 * 64; i += 128) {
        int s = i >> 6, d = i & 63;
        size_t g = ((size_t)(b * 17 + s)) * 1536 + h * 64 + d;
        qs[s][d] = bf2f(qkv[g]); ks[s][d] = bf2f(qkv[g + 512]); vs[s][d] = bf2f(qkv[g + 1024]);
    }
    __syncthreads();
    for (int i = t; i < 17 * 17; i += 128) {
        int r = i / 17, c = i % 17;
        float a = 0.f;
#pragma unroll
        for (int d = 0; d < 64; ++d) a += qs[r][d] * ks[c][d];
        ps[r][c] = a * 0.125f;
    }
    __syncthreads();
    if (t < 17) {
        float mxv = -1e30f;
        for (int c = 0; c < 17; ++c) mxv = fmaxf(mxv, ps[t][c]);
        float sm = 0.f;
        for (int c = 0; c < 17; ++c) { float e = __expf(ps[t][c] - mxv); ps[t][c] = e; sm += e; }
        float inv = 1.f / sm;
        for (int c = 0; c < 17; ++c) ps[t][c] *= inv;
    }
    __syncthreads();
    for (int i = t; i < 17 * 64; i += 128) {
        int s = i >> 6, d = i & 63;
        float a = 0.f;
#pragma unroll
        for (int j = 0; j < 17; ++j) a += ps[s][j] * vs[j][d];
        o[((size_t)(b * 17 + s)) * 512 + h * 64 + d] = f2bf(a);
    }
}

// ---------------- cross-attention: q bf16 (ld 512), kv = enc_kv slice (ld 3072) ----------------
__global__ __launch_bounds__(256)
void k_attn_cross(const u16* __restrict__ q, const u16* __restrict__ kv, u16* __restrict__ o)
{
    int b = blockIdx.x >> 3, h = blockIdx.x & 7;
    __shared__ float qs[17][65];
    __shared__ float ps[17][145];
    int t = threadIdx.x;
    for (int i = t; i < 17 * 64; i += 256) {
        int s = i >> 6, d = i & 63;
        qs[s][d] = bf2f(q[((size_t)(b * 17 + s)) * 512 + h * 64 + d]);
    }
    __syncthreads();
    for (int i = t; i < 17 * 144; i += 256) {
        int r = i / 144, c = i % 144;
        const u16* kr = kv + ((size_t)(b * 144 + c)) * 3072 + h * 64;
        float a = 0.f;
#pragma unroll
        for (int d = 0; d < 64; ++d) a += qs[r][d] * bf2f(kr[d]);
        ps[r][c] = a * 0.125f;
    }
    __syncthreads();
    if (t < 17) {
        float mxv = -1e30f;
        for (int c = 0; c < 144; ++c) mxv = fmaxf(mxv, ps[t][c]);
        float sm = 0.f;
        for (int c = 0; c < 144; ++c) { float e = __expf(ps[t][c] - mxv); ps[t][c] = e; sm += e; }
        float inv = 1.f / sm;
        for (int c = 0; c < 144; ++c) ps[t][c] *= inv;
    }
    __syncthreads();
    for (int i = t; i < 17 * 64; i += 256) {
        int s = i >> 6, d = i & 63;
        float a = 0.f;
        for (int j = 0; j < 144; ++j)
            a += ps[s][j] * bf2f(kv[((size_t)(b * 144 + j)) * 3072 + 512 + h * 64 + d]);
        o[((size_t)(b * 17 + s)) * 512 + h * 64 + d] = f2bf(a);
    }
}

extern "C" void kernel_launch(void* const* d_in, const int* in_sizes, int n_in,
                              void* d_out, int out_size, void* d_ws, size_t ws_size,
                              hipStream_t stream)
{
    (void)in_sizes; (void)out_size;
    if (n_in < 39) return;
    const float* enc    = (const float*)d_in[0];
    const float* wmat   = (const float*)d_in[1];
    const float* i2t_w  = (const float*)d_in[2];
    const float* i2t_b  = (const float*)d_in[3];
    const float* i2t_g  = (const float*)d_in[4];
    const float* i2t_bb = (const float*)d_in[5];
    const float* emb    = (const float*)d_in[6];
    const float* gen_w  = (const float*)d_in[7];
    const float* gen_b  = (const float*)d_in[8];
    const float* a_w    = (const float*)d_in[9];
    const float* a_b    = (const float*)d_in[10];
    const float* fln_g  = (const float*)d_in[11];
    const float* fln_b  = (const float*)d_in[12];
    const float* sa_wq  = (const float*)d_in[13];
    const float* sa_bq  = (const float*)d_in[14];
    const float* sa_wk  = (const float*)d_in[15];
    const float* sa_bk  = (const float*)d_in[16];
    const float* sa_wv  = (const float*)d_in[17];
    const float* sa_bv  = (const float*)d_in[18];
    const float* sa_wo  = (const float*)d_in[19];
    const float* sa_bo  = (const float*)d_in[20];
    const float* ca_wq  = (const float*)d_in[21];
    const float* ca_bq  = (const float*)d_in[22];
    const float* ca_wk  = (const float*)d_in[23];
    const float* ca_bk  = (const float*)d_in[24];
    const float* ca_wv  = (const float*)d_in[25];
    const float* ca_bv  = (const float*)d_in[26];
    const float* ca_wo  = (const float*)d_in[27];
    const float* ca_bo  = (const float*)d_in[28];
    const float* ln1_g  = (const float*)d_in[29];
    const float* ln1_b  = (const float*)d_in[30];
    const float* ln2_g  = (const float*)d_in[31];
    const float* ln2_b  = (const float*)d_in[32];
    const float* ln3_g  = (const float*)d_in[33];
    const float* ln3_b  = (const float*)d_in[34];
    const float* fc1_w  = (const float*)d_in[35];
    const float* fc1_b  = (const float*)d_in[36];
    const float* fc2_w  = (const float*)d_in[37];
    const float* fc2_b  = (const float*)d_in[38];

    char* ws = (char*)d_ws;
    size_t off = 0;
    auto AL = [](size_t x) { return (x + 255) & ~(size_t)255; };
    auto alloc = [&](size_t bytes) { char* p = ws + off; off += AL(bytes); return p; };

    // ---- persistent bf16 transposed weights ----
    u16* i2t_wT  = (u16*)alloc((size_t)512 * 512 * 2);
    u16* sa_qkvT = (u16*)alloc((size_t)3 * 1536 * 512 * 2);
    u16* sa_woT  = (u16*)alloc((size_t)3 * 512 * 512 * 2);
    u16* ca_qT   = (u16*)alloc((size_t)3 * 512 * 512 * 2);
    u16* ca_kvT  = (u16*)alloc((size_t)3 * 1024 * 512 * 2);
    u16* ca_woT  = (u16*)alloc((size_t)3 * 512 * 512 * 2);
    u16* fc1T    = (u16*)alloc((size_t)3 * 2048 * 512 * 2);
    u16* fc2T    = (u16*)alloc((size_t)3 * 512 * 2048 * 2);
    u16* a_wT    = (u16*)alloc((size_t)512 * 1024 * 2);
    u16* gen_wT  = (u16*)alloc((size_t)10112 * 512 * 2);
    u16* embB    = (u16*)alloc((size_t)10112 * 512 * 2);
    u16* embT    = (u16*)alloc((size_t)512 * 10112 * 2);
    u16* enc_bf  = (u16*)alloc((size_t)9216 * 512 * 2);
    float* text_f   = (float*)alloc((size_t)9216 * 512 * 4);
    u16*   text_bf  = (u16*)alloc((size_t)9216 * 512 * 2);
    float* word_emb = (float*)alloc((size_t)9216 * 512 * 4);
    float* rowsum   = (float*)alloc(9216 * 4);
    float* rspart   = (float*)alloc((size_t)79 * 9216 * 4);
    float* sa_qkvB  = (float*)alloc(4608 * 4);
    float* ca_kvB   = (float*)alloc(3072 * 4);

    // ---- decoder-phase buffers ----
    u16* enc_kv = (u16*)alloc((size_t)9216 * 3072 * 2);
    u16* xcat   = (u16*)alloc((size_t)1088 * 1024 * 2);   // cols 0-511: x, 512-1023: x_self
    u16* tqkv   = (u16*)alloc((size_t)1088 * 1536 * 2);
    u16* attnb  = (u16*)alloc((size_t)1088 * 512 * 2);
    u16* q_bf   = (u16*)alloc((size_t)1088 * 512 * 2);
    u16* ffn    = (u16*)alloc((size_t)1088 * 2048 * 2);
    float* x_f   = (float*)alloc((size_t)1088 * 512 * 4);
    float* xs_f  = (float*)alloc((size_t)1088 * 512 * 4);
    float* tmp_f = (float*)alloc((size_t)1088 * 512 * 4);
    float* glin  = (float*)alloc((size_t)1088 * 512 * 4);

    // ---- stage-B chunked region: logits [chunk][10112] bf16 + part [8][chunk][512] f32 ----
    size_t lo = off;
    long budget = (ws_size > lo) ? (long)(ws_size - lo) : 0;
    long perrow = 10112L * 2 + 8L * 512 * 4;
    int chunk = (int)((budget / perrow) & ~(long)127);
    if (chunk > 9216) chunk = 9216;
    if (chunk < 128) chunk = 128;
    u16* logits = (u16*)(ws + lo);
    float* part = (float*)(ws + lo + AL((size_t)chunk * 10112 * 2));
    long pstride = (long)chunk * 512;

    // ---- all weight transposes in ONE launch ----
    TPack tp; int nb_total = 0;
    auto addT = [&](int idx, const float* src, long izs, u16* dst, long ozs,
                    int R, int C, int Rp, int Cp, int ldo, int nz) {
        TD& d = tp.d[idx];
        d.src = src; d.dst = dst; d.izs = izs; d.ozs = ozs;
        d.R = R; d.C = C; d.Rp = Rp; d.Cp = Cp; d.ldo = ldo;
        d.tx = (Cp + 31) / 32; d.ty = (Rp + 31) / 32;
        d.nb = nz * d.tx * d.ty; nb_total += d.nb;
    };
    addT(0,  i2t_w, 0, i2t_wT, 0, 512, 512, 512, 512, 512, 1);
    addT(1,  sa_wq, 512 * 512, sa_qkvT,              1536 * 512, 512, 512, 512, 512, 512, 3);
    addT(2,  sa_wk, 512 * 512, sa_qkvT + 512 * 512,  1536 * 512, 512, 512, 512, 512, 512, 3);
    addT(3,  sa_wv, 512 * 512, sa_qkvT + 1024 * 512, 1536 * 512, 512, 512, 512, 512, 512, 3);
    addT(4,  sa_wo, 512 * 512, sa_woT, 512 * 512, 512, 512, 512, 512, 512, 3);
    addT(5,  ca_wq, 512 * 512, ca_qT,  512 * 512, 512, 512, 512, 512, 512, 3);
    addT(6,  ca_wk, 512 * 512, ca_kvT,             1024 * 512, 512, 512, 512, 512, 512, 3);
    addT(7,  ca_wv, 512 * 512, ca_kvT + 512 * 512, 1024 * 512, 512, 512, 512, 512, 512, 3);
    addT(8,  ca_wo, 512 * 512, ca_woT, 512 * 512, 512, 512, 512, 512, 512, 3);
    addT(9,  fc1_w, (long)512 * 2048, fc1T, (long)2048 * 512, 512, 2048, 512, 2048, 512, 3);
    addT(10, fc2_w, (long)2048 * 512, fc2T, (long)512 * 2048, 2048, 512, 2048, 512, 2048, 3);
    addT(11, a_w, 0, a_wT, 0, 1024, 512, 1024, 512, 1024, 1);
    addT(12, gen_w, 0, gen_wT, 0, 512, 10000, 512, 10112, 512, 1);
    addT(13, emb, 0, embT, 0, 10000, 512, 10112, 512, 10112, 1);
    tp.nd = 14;
    k_mt<<<nb_total, 256, 0, stream>>>(tp);
    k_cvt2<<<4096, 256, 0, stream>>>(emb, embB, 10000 * 512, enc, enc_bf, 9216 * 512);
    k_biaspack<<<18, 256, 0, stream>>>(sa_bq, sa_bk, sa_bv, ca_bk, ca_bv, sa_qkvB, ca_kvB);

    // ---- stage A: text = LN(enc @ i2t_w + b) ----
    k_gemm<128, 128, 64, 64, 0><<<dim3(4, 72), 256, 0, stream>>>(
        enc_bf, 512, i2t_wT, 512, word_emb, 512, nullptr, 0, i2t_b, 0, nullptr,
        9216, 512, 512, 512, 0);
    k_ln<<<9216, 256, 0, stream>>>(word_emb, nullptr, i2t_g, i2t_bb, text_f, text_bf, 512,
                                   nullptr, nullptr);

    // ---- stage B: word_emb = text + softmax(text @ emb^T) @ emb (fused exp, no atomics) ----
    for (int r0 = 0; r0 < 9216; r0 += chunk) {
        int CR = (9216 - r0 < chunk) ? (9216 - r0) : chunk;
        k_gemm<128, 128, 64, 64, 1><<<dim3(79, CR / 128), 256, 0, stream>>>(
            text_bf + (size_t)r0 * 512, 512, embB, 512, nullptr, 0, logits, 10112,
            nullptr, 0, rspart, CR, 10000, 512, 512, 0);
        k_finrs<<<(CR + 255) / 256, 256, 0, stream>>>(rspart, CR, 79, rowsum + r0, CR);
        k_gemm<128, 128, 64, 64, 0><<<dim3(4, CR / 128, 8), 256, 0, stream>>>(
            logits, 10112, embT, 10112, part, 512, nullptr, 0, nullptr, 0, nullptr,
            CR, 512, 10112, 1280, pstride);
        k_reduce_we<<<(CR * 512 + 255) / 256, 256, 0, stream>>>(
            part, pstride, text_f + (size_t)r0 * 512, rowsum + r0,
            word_emb + (size_t)r0 * 512, CR * 512);
    }

    // ---- stage C ----
    k_wmap<<<1088, 256, 0, stream>>>(wmat, word_emb, x_f, xcat);

    // ---- cross K/V for all 3 layers in one GEMM ----
    k_gemm<128, 128, 64, 64, 0><<<dim3(24, 72), 256, 0, stream>>>(
        enc_bf, 512, ca_kvT, 512, nullptr, 0, enc_kv, 3072, ca_kvB, 0, nullptr,
        9216, 3072, 512, 512, 0);

    // ---- stage D: decoder layers (M=1088 = 17 x 64 exactly) ----
    for (int l = 0; l < 3; ++l) {
        size_t wo = (size_t)l * 512 * 512;
        // fused QKV
        k_gemm<64, 64, 32, 32, 0><<<dim3(24, 17), 256, 0, stream>>>(
            xcat, 1024, sa_qkvT + (size_t)l * 1536 * 512, 512, nullptr, 0, tqkv, 1536,
            sa_qkvB + l * 1536, 0, nullptr, 1088, 1536, 512, 512, 0);
        k_attn_self<<<512, 128, 0, stream>>>(tqkv, attnb);
        k_gemm<64, 64, 32, 32, 0><<<dim3(8, 17), 256, 0, stream>>>(
            attnb, 512, sa_woT + wo, 512, xs_f, 512, xcat + 512, 1024,
            sa_bo + l * 512, 0, nullptr, 1088, 512, 512, 512, 0);
        k_ln<<<1088, 256, 0, stream>>>(xs_f, x_f, ln1_g + l * 512, ln1_b + l * 512,
                                       x_f, xcat, 1024, nullptr, nullptr);
        // cross attention
        k_gemm<64, 64, 32, 32, 0><<<dim3(8, 17), 256, 0, stream>>>(
            xcat, 1024, ca_qT + wo, 512, nullptr, 0, q_bf, 512,
            ca_bq + l * 512, 0, nullptr, 1088, 512, 512, 512, 0);
        k_attn_cross<<<512, 256, 0, stream>>>(q_bf, enc_kv + l * 1024, attnb);
        k_gemm<64, 64, 32, 32, 0><<<dim3(8, 17), 256, 0, stream>>>(
            attnb, 512, ca_woT + wo, 512, tmp_f, 512, nullptr, 0,
            ca_bo + l * 512, 0, nullptr, 1088, 512, 512, 512, 0);
        k_ln<<<1088, 256, 0, stream>>>(tmp_f, x_f, ln2_g + l * 512, ln2_b + l * 512,
                                       x_f, xcat, 1024, nullptr, nullptr);
        // FFN
        k_gemm<64, 64, 32, 32, 0><<<dim3(32, 17), 256, 0, stream>>>(
            xcat, 1024, fc1T + (size_t)l * 2048 * 512, 512, nullptr, 0, ffn, 2048,
            fc1_b + l * 2048, 1, nullptr, 1088, 2048, 512, 512, 0);
        k_gemm<64, 64, 32, 32, 0><<<dim3(8, 17), 256, 0, stream>>>(
            ffn, 2048, fc2T + (size_t)l * 512 * 2048, 2048, tmp_f, 512, nullptr, 0,
            fc2_b + l * 512, 0, nullptr, 1088, 512, 2048, 2048, 0);
        k_ln<<<1088, 256, 0, stream>>>(tmp_f, x_f, ln3_g + l * 512, ln3_b + l * 512,
                                       x_f, xcat, 1024, nullptr, nullptr);
    }

    // ---- stage E: gated blend (K=1024 GEMM over [x | x_self]) + fused blend-LN ----
    k_gemm<64, 64, 32, 32, 0><<<dim3(8, 17), 256, 0, stream>>>(
        xcat, 1024, a_wT, 1024, glin, 512, nullptr, 0, a_b, 0, nullptr,
        1088, 512, 1024, 1024, 0);
    k_ln<<<1088, 256, 0, stream>>>(x_f, nullptr, fln_g, fln_b, tmp_f, xcat, 1024,
                                   glin, xs_f);

    // ---- stage F: generator ----
    k_gemm<64, 64, 32, 32, 0><<<dim3(158, 17), 256, 0, stream>>>(
        xcat, 1024, gen_wT, 512, (float*)d_out, 10000, nullptr, 0, gen_b, 0, nullptr,
        1088, 10000, 512, 512, 0);
}